// Round 11
// baseline (38405.719 us; speedup 1.0000x reference)
//
#include <hip/hip_runtime.h>

typedef _Float16 half_t;
typedef _Float16 half2_t __attribute__((ext_vector_type(2)));
typedef _Float16 half4_t __attribute__((ext_vector_type(4)));
typedef _Float16 half8_t __attribute__((ext_vector_type(8)));
typedef float    floatx4 __attribute__((ext_vector_type(4)));

#define T_SEQ 2048
#define EDIM  512

// workspace layout (bytes)
static constexpr size_t EMB_OFF = 0;                       // 32*2048*512 f16 = 67,108,864
static constexpr size_t Q_OFF   = 67108864;                // 2048*512 f16 (x16 aliased during LSTM)
static constexpr size_t WQ_OFF  = Q_OFF  + 2097152;
static constexpr size_t WK_OFF  = WQ_OFF + 524288;
static constexpr size_t WV_OFF  = WK_OFF + 524288;
static constexpr size_t WO_OFF  = WV_OFF + 524288;
static constexpr size_t TE_OFF  = WO_OFF + 524288;         // end 71,335,936
static constexpr size_t FL_OFF  = TE_OFF + 32768;          // 128 ints = 512 B

__device__ __forceinline__ float fdot2f(half2_t a, half2_t b, float c) {
#if __has_builtin(__builtin_amdgcn_fdot2)
  return __builtin_amdgcn_fdot2(a, b, c, false);
#else
  return c + (float)a[0] * (float)b[0] + (float)a[1] * (float)b[1];
#endif
}
__device__ __forceinline__ half2_t mkh2(float a, float b) {
  half2_t r; r[0] = (half_t)a; r[1] = (half_t)b; return r;
}
__device__ __forceinline__ half2_t h2bc(unsigned u) { return __builtin_bit_cast(half2_t, u); }
__device__ __forceinline__ unsigned h2u(half2_t h)  { return __builtin_bit_cast(unsigned, h); }
__device__ __forceinline__ float sigm(float v)  { return __builtin_amdgcn_rcpf(1.f + __expf(-v)); }
__device__ __forceinline__ float tanhf_(float v){ return __builtin_amdgcn_rcpf(1.f + __expf(-2.f * v)) * 2.f - 1.f; }

// ---------------------------------------------------------------------------
// convert fp32 weights + type_emb + x to f16 in workspace (R5-proven)
__global__ void convert_kernel(const float* __restrict__ wq, const float* __restrict__ wk,
                               const float* __restrict__ wvv, const float* __restrict__ wo,
                               const float* __restrict__ te, const float* __restrict__ x,
                               half_t* __restrict__ wq16, half_t* __restrict__ wk16,
                               half_t* __restrict__ wv16, half_t* __restrict__ wo16,
                               half_t* __restrict__ te16, half_t* __restrict__ x16) {
  int i4 = (blockIdx.x * 256 + threadIdx.x) * 4;
  const float* src; half_t* dst; int off;
  if      (i4 < 262144)     { src = wq;  dst = wq16; off = i4; }
  else if (i4 < 2 * 262144) { src = wk;  dst = wk16; off = i4 - 262144; }
  else if (i4 < 3 * 262144) { src = wvv; dst = wv16; off = i4 - 2 * 262144; }
  else if (i4 < 4 * 262144) { src = wo;  dst = wo16; off = i4 - 3 * 262144; }
  else if (i4 < 4 * 262144 + 16384) { src = te; dst = te16; off = i4 - 4 * 262144; }
  else                      { src = x;   dst = x16;  off = i4 - (4 * 262144 + 16384); }
  float4 v = *(const float4*)(src + off);
  half4_t h; h[0] = (half_t)v.x; h[1] = (half_t)v.y; h[2] = (half_t)v.z; h[3] = (half_t)v.w;
  *(half4_t*)(dst + off) = h;
}

// ---------------------------------------------------------------------------
// Split-chain LSTM: chain c = b&63 handled by block pair (c, c+64); block
// half hf=b>>6 owns units [hf*128, hf*128+128). 512 threads = 512 gate rows
// (one row/thread: unit u = hf*128 + t>>2, gate g = t&3). Per-thread weights
// 256 dims = 128 half2: 88 arch VGPRs + 40 in LDS -> ~120 live regs, fits the
// measured 128-arch budget at 2 waves/SIMD with ZERO AGPR tax (R4-R10: any
// >=128-reg weight set got banked in AGPRs, ~2.3x VALU inflation).
// h exchange: g==0 threads write h to emb; publish = per-thread fence +
// barrier + one release-atomic flag; partner spins (normally instant - pair
// runs in lockstep), copies 256B remote slice into hbuf. Gate quad combined
// via 3 shfl_xor. h reads are all-lane-broadcast LDS (no bank cost).
// 128 blocks x 83KB LDS -> 1 block/CU, all resident (no deadlock).
// Pair (b, b+64): 64 % 8 == 0 so both land on the same XCD (perf only).
#define LSTM_LDS_BYTES (10 * 512 * 16 + 2 * 256 * 2)   // 81920 + 1024 = 82944

__global__ __launch_bounds__(512, 1)
void lstm_kernel(const half_t* __restrict__ x16,
                 const float* __restrict__ wih_f, const float* __restrict__ whh_f, const float* __restrict__ b_f,
                 const float* __restrict__ wih_b, const float* __restrict__ whh_b, const float* __restrict__ b_b,
                 half_t* __restrict__ emb, int* __restrict__ flags) {
  extern __shared__ char smem[];
  uint4*  wt   = (uint4*)smem;                   // [10][512] : dims 176..255
  half_t* hbuf = (half_t*)(smem + 81920);        // [2][256]

  const int b = blockIdx.x;
  const int chain = b & 63, hf = b >> 6;
  const int br = chain >> 1, dir = chain & 1;
  const int t = threadIdx.x;
  const int u = hf * 128 + (t >> 2), g = t & 3;
  const float* wih  = dir ? wih_b : wih_f;
  const float* whh  = dir ? whh_b : whh_f;
  const float* bias = dir ? b_b   : b_f;
  const size_t row = (size_t)br * 1024 + g * 256 + u;

  // ---- stage weights: dims 0..175 -> 88 arch half2, dims 176..255 -> LDS ----
  half2_t w[88];
  const float4* wp = (const float4*)(whh + row * 256);
#pragma unroll
  for (int c = 0; c < 44; ++c) {
    float4 v = wp[c];
    w[2 * c]     = mkh2(v.x, v.y);
    w[2 * c + 1] = mkh2(v.z, v.w);
  }
#pragma unroll
  for (int c = 0; c < 10; ++c) {
    float4 a = wp[44 + 2 * c], b2 = wp[45 + 2 * c];
    uint4 uu;
    uu.x = h2u(mkh2(a.x, a.y));   uu.y = h2u(mkh2(a.z, a.w));
    uu.z = h2u(mkh2(b2.x, b2.y)); uu.w = h2u(mkh2(b2.z, b2.w));
    wt[c * 512 + t] = uu;
  }
  half2_t wir[6]; float bb;
  {
    const float* ip = wih + row * 12;
    wir[0] = mkh2(ip[0], ip[1]);  wir[1] = mkh2(ip[2], ip[3]);
    wir[2] = mkh2(ip[4], ip[5]);  wir[3] = mkh2(ip[6], ip[7]);
    wir[4] = mkh2(ip[8], ip[9]);  wir[5] = mkh2(ip[10], ip[11]);
    bb = bias[row];
  }
  hbuf[t] = (half_t)0.f;                         // 512 entries: h_{-1}=0 both buffers
  __syncthreads();

  int* myflag  = flags + b;
  int* remflag = flags + (b ^ 64);
  float cst = 0.f;

  half2_t xh[6];
  {
    const int t0 = dir ? 2047 : 0;
    const uint2* xp = (const uint2*)(x16 + ((size_t)br * T_SEQ + t0) * 12);
    uint2 u0 = xp[0], u1 = xp[1], u2 = xp[2];
    xh[0] = h2bc(u0.x); xh[1] = h2bc(u0.y);
    xh[2] = h2bc(u1.x); xh[3] = h2bc(u1.y);
    xh[4] = h2bc(u2.x); xh[5] = h2bc(u2.y);
  }

#pragma unroll 1
  for (int s = 0; s < T_SEQ; ++s) {
    const int cur = s & 1, nxt = cur ^ 1;
    const int tcur = dir ? (2047 - s) : s;

    // input projection (current xh) then prefetch next x
    float acc = bb;
#pragma unroll
    for (int d = 0; d < 6; ++d) acc = fdot2f(wir[d], xh[d], acc);
    {
      int q1 = s + 1; if (q1 > 2047) q1 = 2047;
      const int tn = dir ? (2047 - q1) : q1;
      const uint2* xp = (const uint2*)(x16 + ((size_t)br * T_SEQ + tn) * 12);
      uint2 u0 = xp[0], u1 = xp[1], u2 = xp[2];
      xh[0] = h2bc(u0.x); xh[1] = h2bc(u0.y);
      xh[2] = h2bc(u1.x); xh[3] = h2bc(u1.y);
      xh[4] = h2bc(u2.x); xh[5] = h2bc(u2.y);
    }

    // recurrent: 32 broadcast h-chunks; 22 against arch weights, 10 vs LDS
    const uint4* hbq = (const uint4*)(hbuf + cur * 256);
#pragma unroll
    for (int c = 0; c < 22; ++c) {
      uint4 hv = hbq[c];
      acc = fdot2f(w[4 * c + 0], h2bc(hv.x), acc);
      acc = fdot2f(w[4 * c + 1], h2bc(hv.y), acc);
      acc = fdot2f(w[4 * c + 2], h2bc(hv.z), acc);
      acc = fdot2f(w[4 * c + 3], h2bc(hv.w), acc);
    }
#pragma unroll
    for (int c = 0; c < 10; ++c) {
      uint4 hv = hbq[22 + c];
      uint4 wv = wt[c * 512 + t];
      acc = fdot2f(h2bc(wv.x), h2bc(hv.x), acc);
      acc = fdot2f(h2bc(wv.y), h2bc(hv.y), acc);
      acc = fdot2f(h2bc(wv.z), h2bc(hv.z), acc);
      acc = fdot2f(h2bc(wv.w), h2bc(hv.w), acc);
    }

    // combine the gate quad (threads t, t^1, t^2, t^3 — same wave)
    float v1 = __shfl_xor(acc, 1);
    float v2 = __shfl_xor(acc, 2);
    float v3 = __shfl_xor(v1, 2);
    if (g == 0) {
      // g==0: acc=i, v1=f, v2=g, v3=o
      cst = sigm(v1) * cst + sigm(acc) * tanhf_(v2);
      float h = sigm(v3) * tanhf_(cst);
      half_t hh = (half_t)h;
      hbuf[nxt * 256 + u] = hh;
      emb[((size_t)br * T_SEQ + tcur) * EDIM + dir * 256 + u] = hh;
    }
    __threadfence();                 // each producer orders its stores
    __syncthreads();
    if (t == 0)
      __hip_atomic_store(myflag, s + 1, __ATOMIC_RELEASE, __HIP_MEMORY_SCOPE_AGENT);

    if (s < 2047) {
      if (t == 0) {
        while (__hip_atomic_load(remflag, __ATOMIC_ACQUIRE, __HIP_MEMORY_SCOPE_AGENT) < s + 1)
          __builtin_amdgcn_s_sleep(1);
      }
      __syncthreads();               // flag observed by all
      if (t < 16) {                  // copy partner's 128 h (256 B) into hbuf
        const uint4* rsrc = (const uint4*)(emb + ((size_t)br * T_SEQ + tcur) * EDIM
                                           + dir * 256 + (1 - hf) * 128) + t;
        *((uint4*)(hbuf + nxt * 256 + (1 - hf) * 128) + t) = *rsrc;
      }
      __syncthreads();               // hbuf[nxt] complete
    }
  }
}

// ---------------------------------------------------------------------------
__global__ __launch_bounds__(256, 1)
void qproj_kernel(const half_t* __restrict__ emb, const half_t* __restrict__ wq16,
                  const float* __restrict__ bq, half_t* __restrict__ q_ws) {
  const int t0 = blockIdx.x * 32;
  const int tid = threadIdx.x;
  const int lane = tid & 63, wid = tid >> 6;
  const int col = lane & 15, grp = lane >> 4;

  floatx4 acc[2][8];
#pragma unroll
  for (int nt = 0; nt < 8; ++nt) {
    int eo = wid * 128 + nt * 16 + col;
    float b = bq[eo];
#pragma unroll
    for (int mt = 0; mt < 2; ++mt) { acc[mt][nt][0] = b; acc[mt][nt][1] = b; acc[mt][nt][2] = b; acc[mt][nt][3] = b; }
  }
  for (int kc = 0; kc < 16; ++kc) {
    const int e = kc * 32 + grp * 8;
    half8_t a[2];
#pragma unroll
    for (int mt = 0; mt < 2; ++mt) {
      int trow = t0 + mt * 16 + col;
      a[mt] = *(const half8_t*)(emb + (size_t)trow * EDIM + e);
    }
#pragma unroll
    for (int nt = 0; nt < 8; ++nt) {
      int eo = wid * 128 + nt * 16 + col;
      half8_t bf = *(const half8_t*)(wq16 + (size_t)eo * EDIM + e);
#pragma unroll
      for (int mt = 0; mt < 2; ++mt)
        acc[mt][nt] = __builtin_amdgcn_mfma_f32_16x16x32_f16(a[mt], bf, acc[mt][nt], 0, 0, 0);
    }
  }
#pragma unroll
  for (int mt = 0; mt < 2; ++mt)
#pragma unroll
    for (int nt = 0; nt < 8; ++nt)
#pragma unroll
      for (int r = 0; r < 4; ++r) {
        int trow = t0 + mt * 16 + grp * 4 + r;
        int eo = wid * 128 + nt * 16 + col;
        q_ws[(size_t)trow * EDIM + eo] = (half_t)acc[mt][nt][r];
      }
}

// ---------------------------------------------------------------------------
__global__ __launch_bounds__(256, 1)
void attn_kernel(const half_t* __restrict__ emb, const half_t* __restrict__ q_ws,
                 const half_t* __restrict__ wk16, const half_t* __restrict__ wv16,
                 const half_t* __restrict__ wo16, const half_t* __restrict__ te16,
                 const float* __restrict__ bk, const float* __restrict__ bv,
                 const float* __restrict__ bo, float* __restrict__ out) {
  __shared__ float  scores_lds[128];
  __shared__ float  w_lds[128];
  __shared__ half_t ctx_lds[512];

  const int t = blockIdx.x;
  const int tid = threadIdx.x;
  const int lane = tid & 63, wid = tid >> 6;
  const int col = lane & 15, grp = lane >> 4;

  floatx4 kacc[2][8], vacc[2][8];
#pragma unroll
  for (int nt = 0; nt < 8; ++nt) {
    int eo = wid * 128 + nt * 16 + col;
    float kb = bk[eo], vb = bv[eo];
#pragma unroll
    for (int mt = 0; mt < 2; ++mt) {
      kacc[mt][nt][0] = kb; kacc[mt][nt][1] = kb; kacc[mt][nt][2] = kb; kacc[mt][nt][3] = kb;
      vacc[mt][nt][0] = vb; vacc[mt][nt][1] = vb; vacc[mt][nt][2] = vb; vacc[mt][nt][3] = vb;
    }
  }
  for (int kc = 0; kc < 16; ++kc) {
    const int e = kc * 32 + grp * 8;
    half8_t av[2], ak[2];
#pragma unroll
    for (int mt = 0; mt < 2; ++mt) {
      int branch = mt * 16 + col;
      av[mt] = *(const half8_t*)(emb + ((size_t)branch * T_SEQ + t) * EDIM + e);
      half8_t te = *(const half8_t*)(te16 + (size_t)branch * EDIM + e);
      ak[mt] = av[mt] + te;
    }
#pragma unroll
    for (int nt = 0; nt < 8; ++nt) {
      int eo = wid * 128 + nt * 16 + col;
      half8_t bkf = *(const half8_t*)(wk16 + (size_t)eo * EDIM + e);
      half8_t bvf = *(const half8_t*)(wv16 + (size_t)eo * EDIM + e);
#pragma unroll
      for (int mt = 0; mt < 2; ++mt) {
        kacc[mt][nt] = __builtin_amdgcn_mfma_f32_16x16x32_f16(ak[mt], bkf, kacc[mt][nt], 0, 0, 0);
        vacc[mt][nt] = __builtin_amdgcn_mfma_f32_16x16x32_f16(av[mt], bvf, vacc[mt][nt], 0, 0, 0);
      }
    }
  }

  float spart[8];
#pragma unroll
  for (int i = 0; i < 8; ++i) spart[i] = 0.f;
#pragma unroll
  for (int nt = 0; nt < 8; ++nt) {
    int eo = wid * 128 + nt * 16 + col;
    float qf = (float)q_ws[(size_t)t * EDIM + eo];
#pragma unroll
    for (int mt = 0; mt < 2; ++mt)
#pragma unroll
      for (int r = 0; r < 4; ++r)
        spart[mt * 4 + r] += qf * kacc[mt][nt][r];
  }
#pragma unroll
  for (int i = 0; i < 8; ++i) {
    float v = spart[i];
    v += __shfl_xor(v, 1); v += __shfl_xor(v, 2); v += __shfl_xor(v, 4); v += __shfl_xor(v, 8);
    spart[i] = v;
  }
  const float scale = 0.08838834764831845f;
  if (col == 0) {
#pragma unroll
    for (int mt = 0; mt < 2; ++mt)
#pragma unroll
      for (int r = 0; r < 4; ++r)
        scores_lds[wid * 32 + mt * 16 + grp * 4 + r] = spart[mt * 4 + r] * scale;
  }
  float sc = scores_lds[wid * 32 + (lane & 31)];
  float m = sc;
  m = fmaxf(m, __shfl_xor(m, 1));  m = fmaxf(m, __shfl_xor(m, 2));
  m = fmaxf(m, __shfl_xor(m, 4));  m = fmaxf(m, __shfl_xor(m, 8));
  m = fmaxf(m, __shfl_xor(m, 16));
  float ex = __expf(sc - m);
  float sm = ex;
  sm += __shfl_xor(sm, 1); sm += __shfl_xor(sm, 2); sm += __shfl_xor(sm, 4);
  sm += __shfl_xor(sm, 8); sm += __shfl_xor(sm, 16);
  float wn = ex * __builtin_amdgcn_rcpf(sm);
  if (lane < 32) w_lds[wid * 32 + lane] = wn;

  float wb[8];
#pragma unroll
  for (int mt = 0; mt < 2; ++mt)
#pragma unroll
    for (int r = 0; r < 4; ++r)
      wb[mt * 4 + r] = w_lds[wid * 32 + mt * 16 + grp * 4 + r];
#pragma unroll
  for (int nt = 0; nt < 8; ++nt) {
    float cx = 0.f;
#pragma unroll
    for (int mt = 0; mt < 2; ++mt)
#pragma unroll
      for (int r = 0; r < 4; ++r)
        cx += wb[mt * 4 + r] * vacc[mt][nt][r];
    cx += __shfl_xor(cx, 16);
    cx += __shfl_xor(cx, 32);
    float cxh = __shfl_xor(cx, 1);
    if ((lane < 16) && ((lane & 1) == 0))
      *(half2_t*)(ctx_lds + wid * 128 + nt * 16 + lane) = mkh2(cx, cxh);
  }
  __syncthreads();

  if (tid < 32) {
    float a = 0.25f * (w_lds[tid] + w_lds[32 + tid] + w_lds[64 + tid] + w_lds[96 + tid]);
    out[1048576 + (size_t)t * 32 + tid] = a;
  }
  const int eo2 = tid * 2;
  float o0 = bo[eo2], o1 = bo[eo2 + 1];
  const uint4* cl2 = (const uint4*)ctx_lds;
  const half_t* wrow0 = wo16 + (size_t)eo2 * EDIM;
  const half_t* wrow1 = wrow0 + EDIM;
#pragma unroll 8
  for (int c = 0; c < 64; ++c) {
    uint4 cv = cl2[c];
    uint4 w0 = *(const uint4*)(wrow0 + c * 8);
    uint4 w1 = *(const uint4*)(wrow1 + c * 8);
    half2_t c0 = h2bc(cv.x), c1 = h2bc(cv.y), c2 = h2bc(cv.z), c3 = h2bc(cv.w);
    o0 = fdot2f(h2bc(w0.x), c0, o0);
    o0 = fdot2f(h2bc(w0.y), c1, o0);
    o0 = fdot2f(h2bc(w0.z), c2, o0);
    o0 = fdot2f(h2bc(w0.w), c3, o0);
    o1 = fdot2f(h2bc(w1.x), c0, o1);
    o1 = fdot2f(h2bc(w1.y), c1, o1);
    o1 = fdot2f(h2bc(w1.z), c2, o1);
    o1 = fdot2f(h2bc(w1.w), c3, o1);
  }
  out[(size_t)t * EDIM + eo2]     = o0;
  out[(size_t)t * EDIM + eo2 + 1] = o1;
}

// ---------------------------------------------------------------------------
extern "C" void kernel_launch(void* const* d_in, const int* in_sizes, int n_in,
                              void* d_out, int out_size, void* d_ws, size_t ws_size,
                              hipStream_t stream) {
  const float* x    = (const float*)d_in[0];
  const float* wihf = (const float*)d_in[1];
  const float* whhf = (const float*)d_in[2];
  const float* bf   = (const float*)d_in[3];
  const float* wihb = (const float*)d_in[4];
  const float* whhb = (const float*)d_in[5];
  const float* bbv  = (const float*)d_in[6];
  const float* te   = (const float*)d_in[7];
  const float* wq   = (const float*)d_in[8];
  const float* bq   = (const float*)d_in[9];
  const float* wk   = (const float*)d_in[10];
  const float* bk   = (const float*)d_in[11];
  const float* wvv  = (const float*)d_in[12];
  const float* bv   = (const float*)d_in[13];
  const float* wo   = (const float*)d_in[14];
  const float* bo   = (const float*)d_in[15];
  float* out = (float*)d_out;

  char* ws = (char*)d_ws;
  half_t* emb  = (half_t*)(ws + EMB_OFF);
  half_t* q_ws = (half_t*)(ws + Q_OFF);
  half_t* x16  = (half_t*)(ws + Q_OFF);     // aliased during LSTM phase
  half_t* wq16 = (half_t*)(ws + WQ_OFF);
  half_t* wk16 = (half_t*)(ws + WK_OFF);
  half_t* wv16 = (half_t*)(ws + WV_OFF);
  half_t* wo16 = (half_t*)(ws + WO_OFF);
  half_t* te16 = (half_t*)(ws + TE_OFF);
  int*    flags = (int*)(ws + FL_OFF);

  convert_kernel<<<1808, 256, 0, stream>>>(wq, wk, wvv, wo, te, x,
                                           wq16, wk16, wv16, wo16, te16, x16);

  (void)hipMemsetAsync(flags, 0, 128 * sizeof(int), stream);

  (void)hipFuncSetAttribute((const void*)lstm_kernel,
                            hipFuncAttributeMaxDynamicSharedMemorySize, LSTM_LDS_BYTES);
  lstm_kernel<<<128, 512, LSTM_LDS_BYTES, stream>>>(x16, wihf, whhf, bf,
                                                    wihb, whhb, bbv, emb, flags);

  qproj_kernel<<<64, 256, 0, stream>>>(emb, wq16, bq, q_ws);

  attn_kernel<<<2048, 256, 0, stream>>>(emb, q_ws, wk16, wv16, wo16, te16, bk, bv, bo, out);
}

// Round 12
// 4606.104 us; speedup vs baseline: 8.3380x; 8.3380x over previous
//
#include <hip/hip_runtime.h>

typedef _Float16 half_t;
typedef _Float16 half2_t __attribute__((ext_vector_type(2)));
typedef _Float16 half4_t __attribute__((ext_vector_type(4)));
typedef _Float16 half8_t __attribute__((ext_vector_type(8)));
typedef float    floatx4 __attribute__((ext_vector_type(4)));

#define T_SEQ 2048
#define EDIM  512

// workspace layout (bytes). total required ~71.4 MB
static constexpr size_t EMB_OFF = 0;                       // 32*2048*512 f16 = 67,108,864
static constexpr size_t Q_OFF   = 67108864;                // 2048*512 f16 (x16 aliased during LSTM)
static constexpr size_t WQ_OFF  = Q_OFF  + 2097152;
static constexpr size_t WK_OFF  = WQ_OFF + 524288;
static constexpr size_t WV_OFF  = WK_OFF + 524288;
static constexpr size_t WO_OFF  = WV_OFF + 524288;
static constexpr size_t TE_OFF  = WO_OFF + 524288;         // end 71,335,936

__device__ __forceinline__ float fdot2f(half2_t a, half2_t b, float c) {
#if __has_builtin(__builtin_amdgcn_fdot2)
  return __builtin_amdgcn_fdot2(a, b, c, false);
#else
  return c + (float)a[0] * (float)b[0] + (float)a[1] * (float)b[1];
#endif
}
__device__ __forceinline__ half2_t mkh2(float a, float b) {
  half2_t r; r[0] = (half_t)a; r[1] = (half_t)b; return r;
}
__device__ __forceinline__ half2_t h2bc(unsigned u) { return __builtin_bit_cast(half2_t, u); }
__device__ __forceinline__ unsigned h2u(half2_t h)  { return __builtin_bit_cast(unsigned, h); }
__device__ __forceinline__ float sigm(float v)  { return __builtin_amdgcn_rcpf(1.f + __expf(-v)); }
__device__ __forceinline__ float tanhf_(float v){ return __builtin_amdgcn_rcpf(1.f + __expf(-2.f * v)) * 2.f - 1.f; }

// explicit AGPR pinning: def in AGPR at staging, one accvgpr_read per use.
// volatile so LICM cannot hoist the 116 reads out of the step loop (which
// would materialize them all in VGPRs and spill).
__device__ __forceinline__ unsigned ag_write(unsigned v) {
  unsigned a;
  asm volatile("v_accvgpr_write_b32 %0, %1" : "=a"(a) : "v"(v));
  return a;
}
__device__ __forceinline__ half2_t ag_read(unsigned a) {
  unsigned v;
  asm volatile("v_accvgpr_read_b32 %0, %1" : "=v"(v) : "a"(a));
  return h2bc(v);
}

// ---------------------------------------------------------------------------
// convert fp32 weights + type_emb + x to f16 in workspace (R5-proven)
__global__ void convert_kernel(const float* __restrict__ wq, const float* __restrict__ wk,
                               const float* __restrict__ wvv, const float* __restrict__ wo,
                               const float* __restrict__ te, const float* __restrict__ x,
                               half_t* __restrict__ wq16, half_t* __restrict__ wk16,
                               half_t* __restrict__ wv16, half_t* __restrict__ wo16,
                               half_t* __restrict__ te16, half_t* __restrict__ x16) {
  int i4 = (blockIdx.x * 256 + threadIdx.x) * 4;
  const float* src; half_t* dst; int off;
  if      (i4 < 262144)     { src = wq;  dst = wq16; off = i4; }
  else if (i4 < 2 * 262144) { src = wk;  dst = wk16; off = i4 - 262144; }
  else if (i4 < 3 * 262144) { src = wvv; dst = wv16; off = i4 - 2 * 262144; }
  else if (i4 < 4 * 262144) { src = wo;  dst = wo16; off = i4 - 3 * 262144; }
  else if (i4 < 4 * 262144 + 16384) { src = te; dst = te16; off = i4 - 4 * 262144; }
  else                      { src = x;   dst = x16;  off = i4 - (4 * 262144 + 16384); }
  float4 v = *(const float4*)(src + off);
  half4_t h; h[0] = (half_t)v.x; h[1] = (half_t)v.y; h[2] = (half_t)v.z; h[3] = (half_t)v.w;
  *(half4_t*)(dst + off) = h;
}

// ---------------------------------------------------------------------------
// LSTM (R7 skeleton + explicit 3-way weight homing). One (branch,dir) chain
// per block, 512 threads. Thread t: unit j=t>>1, h-half hf=t&1; 4 gate rows
// x 128 h-dims = 256 half2 weights/thread. Storage identity per CU: 512KB
// W_hh vs 256KB arch regs + 160KB LDS -> ~96KB MUST live in AGPRs. Split per
// row (64 half2): chunks c=0..3 arch (16), c=4..4+nag AGPR (28; row3 32),
// rest LDS (20; row3 16). Arch ask 64+~50 working <= 128 budget (2 w/SIMD law:
// R1/R4/R9 measured 256/128/64) -> no silent overflow; AGPR 116 <= 128 with
// controlled 1-read-per-use tax (R4-R7's default overflow handling cost
// ~2.3x VALU); LDS 19 uint4 slots = 152KB.
// hbuf halves padded 16B apart: R5-verified 0 bank conflicts.
#define HB_STRIDE 272
#define LSTM_LDS_BYTES (19 * 512 * 16 + 2 * HB_STRIDE * 2)  // 155648 + 1088 = 156736

__global__ __launch_bounds__(512, 1)
void lstm_kernel(const half_t* __restrict__ x16,
                 const float* __restrict__ wih_f, const float* __restrict__ whh_f, const float* __restrict__ b_f,
                 const float* __restrict__ wih_b, const float* __restrict__ whh_b, const float* __restrict__ b_b,
                 half_t* __restrict__ emb) {
  extern __shared__ char smem[];
  uint4*  wt   = (uint4*)smem;                     // [19 slots][512 threads]
  half_t* hbuf = (half_t*)(smem + 19 * 512 * 16);  // [2][HB_STRIDE]

  const int bid = blockIdx.x;
  const int n = bid >> 1, dir = bid & 1;
  const int t = threadIdx.x;
  const int j = t >> 1, hf = t & 1;
  const float* wih  = dir ? wih_b : wih_f;
  const float* whh  = dir ? whh_b : whh_f;
  const float* bias = dir ? b_b   : b_f;

  half2_t  w[4][16];     // arch: chunks 0..3 per row
  unsigned wag[4][32];   // AGPR: chunks 4..4+nag per row (rows 0-2: 28, row 3: 32)
  half2_t  wir[2][6];
  float    bb0, bb1;

#pragma unroll
  for (int r = 0; r < 4; ++r) {
    const size_t row = (size_t)n * 1024 + r * 256 + j;
    const float4* wp = (const float4*)(whh + row * 256 + hf * 128);
    const int nag = (r == 3) ? 8 : 7;      // AGPR chunks this row
    const int nl  = 12 - nag;              // LDS chunks this row (5 or 4)
#pragma unroll
    for (int f = 0; f < 8; ++f) {          // arch: float4 0..7 -> half2 0..15
      float4 v = wp[f];
      w[r][2 * f]     = mkh2(v.x, v.y);
      w[r][2 * f + 1] = mkh2(v.z, v.w);
    }
#pragma unroll
    for (int f = 0; f < 16; ++f) {         // AGPR: float4 8..8+2*nag-1
      if (f < 2 * nag) {
        float4 v = wp[8 + f];
        wag[r][2 * f]     = ag_write(h2u(mkh2(v.x, v.y)));
        wag[r][2 * f + 1] = ag_write(h2u(mkh2(v.z, v.w)));
      }
    }
#pragma unroll
    for (int cc = 0; cc < 5; ++cc) {       // LDS: remaining float4s
      if (cc < nl) {
        float4 a = wp[8 + 2 * nag + 2 * cc], b2 = wp[9 + 2 * nag + 2 * cc];
        uint4 u;
        u.x = h2u(mkh2(a.x, a.y));   u.y = h2u(mkh2(a.z, a.w));
        u.z = h2u(mkh2(b2.x, b2.y)); u.w = h2u(mkh2(b2.z, b2.w));
        wt[((r < 3 ? r * 5 : 15) + cc) * 512 + t] = u;
      }
    }
  }
  {
    const int rbase = hf * 2;              // even lanes: gates i,f; odd: g,o
#pragma unroll
    for (int rr = 0; rr < 2; ++rr) {
      const size_t row = (size_t)n * 1024 + (rbase + rr) * 256 + j;
      const float4* ip = (const float4*)(wih + row * 12);
      float4 a = ip[0], b2 = ip[1], c4 = ip[2];
      wir[rr][0] = mkh2(a.x, a.y);   wir[rr][1] = mkh2(a.z, a.w);
      wir[rr][2] = mkh2(b2.x, b2.y); wir[rr][3] = mkh2(b2.z, b2.w);
      wir[rr][4] = mkh2(c4.x, c4.y); wir[rr][5] = mkh2(c4.z, c4.w);
    }
    bb0 = bias[(size_t)n * 1024 + (rbase + 0) * 256 + j];
    bb1 = bias[(size_t)n * 1024 + (rbase + 1) * 256 + j];
  }
  if (t < 2 * HB_STRIDE) hbuf[t] = (half_t)0.f;
  __syncthreads();

  float cst = 0.f;
  half2_t xh[6];
  {
    const int t0 = dir ? 2047 : 0;
    const uint2* xp = (const uint2*)(x16 + ((size_t)n * T_SEQ + t0) * 12);
    uint2 u0 = xp[0], u1 = xp[1], u2 = xp[2];
    xh[0] = h2bc(u0.x); xh[1] = h2bc(u0.y);
    xh[2] = h2bc(u1.x); xh[3] = h2bc(u1.y);
    xh[4] = h2bc(u2.x); xh[5] = h2bc(u2.y);
  }

#pragma unroll 1
  for (int s = 0; s < T_SEQ; ++s) {
    const int tcur = dir ? (2047 - s) : s;
    int tnext = dir ? (2046 - s) : (s + 1);
    if (s == 2047) tnext = tcur;

    // input projection for this thread's 2 owned gate rows
    float p0 = bb0, p1 = bb1;
#pragma unroll
    for (int d = 0; d < 6; ++d) {
      p0 = fdot2f(wir[0][d], xh[d], p0);
      p1 = fdot2f(wir[1][d], xh[d], p1);
    }
    // prefetch next x; hides under the recurrent section
    {
      const uint2* xnp = (const uint2*)(x16 + ((size_t)n * T_SEQ + tnext) * 12);
      uint2 u0 = xnp[0], u1 = xnp[1], u2 = xnp[2];
      xh[0] = h2bc(u0.x); xh[1] = h2bc(u0.y);
      xh[2] = h2bc(u1.x); xh[3] = h2bc(u1.y);
      xh[4] = h2bc(u2.x); xh[5] = h2bc(u2.y);
    }

    float acc[4];
    acc[0] = hf ? 0.f : p0;
    acc[1] = hf ? 0.f : p1;
    acc[2] = hf ? p0 : 0.f;
    acc[3] = hf ? p1 : 0.f;

    // recurrent: 16 uint4 h-chunks over this thread's 128 dims
    const uint4* hb = (const uint4*)(hbuf + (s & 1) * HB_STRIDE) + hf * 17;
#pragma unroll
    for (int c = 0; c < 16; ++c) {
      uint4 hv = hb[c];
      half2_t h0 = h2bc(hv.x), h1 = h2bc(hv.y), h2 = h2bc(hv.z), h3 = h2bc(hv.w);
#pragma unroll
      for (int r = 0; r < 4; ++r) {
        const int nag = (r == 3) ? 8 : 7;
        if (c < 4) {                       // arch weights
          acc[r] = fdot2f(w[r][4 * c + 0], h0, acc[r]);
          acc[r] = fdot2f(w[r][4 * c + 1], h1, acc[r]);
          acc[r] = fdot2f(w[r][4 * c + 2], h2, acc[r]);
          acc[r] = fdot2f(w[r][4 * c + 3], h3, acc[r]);
        } else if (c < 4 + nag) {          // AGPR weights: 1 read + 1 dot each
          const int bse = (c - 4) * 4;
          acc[r] = fdot2f(ag_read(wag[r][bse + 0]), h0, acc[r]);
          acc[r] = fdot2f(ag_read(wag[r][bse + 1]), h1, acc[r]);
          acc[r] = fdot2f(ag_read(wag[r][bse + 2]), h2, acc[r]);
          acc[r] = fdot2f(ag_read(wag[r][bse + 3]), h3, acc[r]);
        } else {                           // LDS weights
          const int slot = (r < 3 ? r * 5 : 15) + (c - 4 - nag);
          uint4 wv = wt[slot * 512 + t];
          acc[r] = fdot2f(h2bc(wv.x), h0, acc[r]);
          acc[r] = fdot2f(h2bc(wv.y), h1, acc[r]);
          acc[r] = fdot2f(h2bc(wv.z), h2, acc[r]);
          acc[r] = fdot2f(h2bc(wv.w), h3, acc[r]);
        }
      }
    }

    // combine pair partials (t and t^1 in the same wave)
    acc[0] += __shfl_xor(acc[0], 1);
    acc[1] += __shfl_xor(acc[1], 1);
    acc[2] += __shfl_xor(acc[2], 1);
    acc[3] += __shfl_xor(acc[3], 1);

    float si = sigm(acc[0]), sf = sigm(acc[1]), gg = tanhf_(acc[2]), so = sigm(acc[3]);
    cst = sf * cst + si * gg;
    float h = so * tanhf_(cst);
    if (!hf) {
      half_t hh = (half_t)h;
      const int pos = j + ((j >> 7) << 3);
      hbuf[((s + 1) & 1) * HB_STRIDE + pos] = hh;
      emb[((size_t)n * T_SEQ + tcur) * EDIM + dir * 256 + j] = hh;
    }
    __syncthreads();
  }
}

// ---------------------------------------------------------------------------
__global__ __launch_bounds__(256, 1)
void qproj_kernel(const half_t* __restrict__ emb, const half_t* __restrict__ wq16,
                  const float* __restrict__ bq, half_t* __restrict__ q_ws) {
  const int t0 = blockIdx.x * 32;
  const int tid = threadIdx.x;
  const int lane = tid & 63, wid = tid >> 6;
  const int col = lane & 15, grp = lane >> 4;

  floatx4 acc[2][8];
#pragma unroll
  for (int nt = 0; nt < 8; ++nt) {
    int eo = wid * 128 + nt * 16 + col;
    float b = bq[eo];
#pragma unroll
    for (int mt = 0; mt < 2; ++mt) { acc[mt][nt][0] = b; acc[mt][nt][1] = b; acc[mt][nt][2] = b; acc[mt][nt][3] = b; }
  }
  for (int kc = 0; kc < 16; ++kc) {
    const int e = kc * 32 + grp * 8;
    half8_t a[2];
#pragma unroll
    for (int mt = 0; mt < 2; ++mt) {
      int trow = t0 + mt * 16 + col;
      a[mt] = *(const half8_t*)(emb + (size_t)trow * EDIM + e);
    }
#pragma unroll
    for (int nt = 0; nt < 8; ++nt) {
      int eo = wid * 128 + nt * 16 + col;
      half8_t bf = *(const half8_t*)(wq16 + (size_t)eo * EDIM + e);
#pragma unroll
      for (int mt = 0; mt < 2; ++mt)
        acc[mt][nt] = __builtin_amdgcn_mfma_f32_16x16x32_f16(a[mt], bf, acc[mt][nt], 0, 0, 0);
    }
  }
#pragma unroll
  for (int mt = 0; mt < 2; ++mt)
#pragma unroll
    for (int nt = 0; nt < 8; ++nt)
#pragma unroll
      for (int r = 0; r < 4; ++r) {
        int trow = t0 + mt * 16 + grp * 4 + r;
        int eo = wid * 128 + nt * 16 + col;
        q_ws[(size_t)trow * EDIM + eo] = (half_t)acc[mt][nt][r];
      }
}

// ---------------------------------------------------------------------------
__global__ __launch_bounds__(256, 1)
void attn_kernel(const half_t* __restrict__ emb, const half_t* __restrict__ q_ws,
                 const half_t* __restrict__ wk16, const half_t* __restrict__ wv16,
                 const half_t* __restrict__ wo16, const half_t* __restrict__ te16,
                 const float* __restrict__ bk, const float* __restrict__ bv,
                 const float* __restrict__ bo, float* __restrict__ out) {
  __shared__ float  scores_lds[128];
  __shared__ float  w_lds[128];
  __shared__ half_t ctx_lds[512];

  const int t = blockIdx.x;
  const int tid = threadIdx.x;
  const int lane = tid & 63, wid = tid >> 6;
  const int col = lane & 15, grp = lane >> 4;

  floatx4 kacc[2][8], vacc[2][8];
#pragma unroll
  for (int nt = 0; nt < 8; ++nt) {
    int eo = wid * 128 + nt * 16 + col;
    float kb = bk[eo], vb = bv[eo];
#pragma unroll
    for (int mt = 0; mt < 2; ++mt) {
      kacc[mt][nt][0] = kb; kacc[mt][nt][1] = kb; kacc[mt][nt][2] = kb; kacc[mt][nt][3] = kb;
      vacc[mt][nt][0] = vb; vacc[mt][nt][1] = vb; vacc[mt][nt][2] = vb; vacc[mt][nt][3] = vb;
    }
  }
  for (int kc = 0; kc < 16; ++kc) {
    const int e = kc * 32 + grp * 8;
    half8_t av[2], ak[2];
#pragma unroll
    for (int mt = 0; mt < 2; ++mt) {
      int branch = mt * 16 + col;
      av[mt] = *(const half8_t*)(emb + ((size_t)branch * T_SEQ + t) * EDIM + e);
      half8_t te = *(const half8_t*)(te16 + (size_t)branch * EDIM + e);
      ak[mt] = av[mt] + te;
    }
#pragma unroll
    for (int nt = 0; nt < 8; ++nt) {
      int eo = wid * 128 + nt * 16 + col;
      half8_t bkf = *(const half8_t*)(wk16 + (size_t)eo * EDIM + e);
      half8_t bvf = *(const half8_t*)(wv16 + (size_t)eo * EDIM + e);
#pragma unroll
      for (int mt = 0; mt < 2; ++mt) {
        kacc[mt][nt] = __builtin_amdgcn_mfma_f32_16x16x32_f16(ak[mt], bkf, kacc[mt][nt], 0, 0, 0);
        vacc[mt][nt] = __builtin_amdgcn_mfma_f32_16x16x32_f16(av[mt], bvf, vacc[mt][nt], 0, 0, 0);
      }
    }
  }

  float spart[8];
#pragma unroll
  for (int i = 0; i < 8; ++i) spart[i] = 0.f;
#pragma unroll
  for (int nt = 0; nt < 8; ++nt) {
    int eo = wid * 128 + nt * 16 + col;
    float qf = (float)q_ws[(size_t)t * EDIM + eo];
#pragma unroll
    for (int mt = 0; mt < 2; ++mt)
#pragma unroll
      for (int r = 0; r < 4; ++r)
        spart[mt * 4 + r] += qf * kacc[mt][nt][r];
  }
#pragma unroll
  for (int i = 0; i < 8; ++i) {
    float v = spart[i];
    v += __shfl_xor(v, 1); v += __shfl_xor(v, 2); v += __shfl_xor(v, 4); v += __shfl_xor(v, 8);
    spart[i] = v;
  }
  const float scale = 0.08838834764831845f;
  if (col == 0) {
#pragma unroll
    for (int mt = 0; mt < 2; ++mt)
#pragma unroll
      for (int r = 0; r < 4; ++r)
        scores_lds[wid * 32 + mt * 16 + grp * 4 + r] = spart[mt * 4 + r] * scale;
  }
  float sc = scores_lds[wid * 32 + (lane & 31)];
  float m = sc;
  m = fmaxf(m, __shfl_xor(m, 1));  m = fmaxf(m, __shfl_xor(m, 2));
  m = fmaxf(m, __shfl_xor(m, 4));  m = fmaxf(m, __shfl_xor(m, 8));
  m = fmaxf(m, __shfl_xor(m, 16));
  float ex = __expf(sc - m);
  float sm = ex;
  sm += __shfl_xor(sm, 1); sm += __shfl_xor(sm, 2); sm += __shfl_xor(sm, 4);
  sm += __shfl_xor(sm, 8); sm += __shfl_xor(sm, 16);
  float wn = ex * __builtin_amdgcn_rcpf(sm);
  if (lane < 32) w_lds[wid * 32 + lane] = wn;

  float wb[8];
#pragma unroll
  for (int mt = 0; mt < 2; ++mt)
#pragma unroll
    for (int r = 0; r < 4; ++r)
      wb[mt * 4 + r] = w_lds[wid * 32 + mt * 16 + grp * 4 + r];
#pragma unroll
  for (int nt = 0; nt < 8; ++nt) {
    float cx = 0.f;
#pragma unroll
    for (int mt = 0; mt < 2; ++mt)
#pragma unroll
      for (int r = 0; r < 4; ++r)
        cx += wb[mt * 4 + r] * vacc[mt][nt][r];
    cx += __shfl_xor(cx, 16);
    cx += __shfl_xor(cx, 32);
    float cxh = __shfl_xor(cx, 1);
    if ((lane < 16) && ((lane & 1) == 0))
      *(half2_t*)(ctx_lds + wid * 128 + nt * 16 + lane) = mkh2(cx, cxh);
  }
  __syncthreads();

  if (tid < 32) {
    float a = 0.25f * (w_lds[tid] + w_lds[32 + tid] + w_lds[64 + tid] + w_lds[96 + tid]);
    out[1048576 + (size_t)t * 32 + tid] = a;
  }
  const int eo2 = tid * 2;
  float o0 = bo[eo2], o1 = bo[eo2 + 1];
  const uint4* cl2 = (const uint4*)ctx_lds;
  const half_t* wrow0 = wo16 + (size_t)eo2 * EDIM;
  const half_t* wrow1 = wrow0 + EDIM;
#pragma unroll 8
  for (int c = 0; c < 64; ++c) {
    uint4 cv = cl2[c];
    uint4 w0 = *(const uint4*)(wrow0 + c * 8);
    uint4 w1 = *(const uint4*)(wrow1 + c * 8);
    half2_t c0 = h2bc(cv.x), c1 = h2bc(cv.y), c2 = h2bc(cv.z), c3 = h2bc(cv.w);
    o0 = fdot2f(h2bc(w0.x), c0, o0);
    o0 = fdot2f(h2bc(w0.y), c1, o0);
    o0 = fdot2f(h2bc(w0.z), c2, o0);
    o0 = fdot2f(h2bc(w0.w), c3, o0);
    o1 = fdot2f(h2bc(w1.x), c0, o1);
    o1 = fdot2f(h2bc(w1.y), c1, o1);
    o1 = fdot2f(h2bc(w1.z), c2, o1);
    o1 = fdot2f(h2bc(w1.w), c3, o1);
  }
  out[(size_t)t * EDIM + eo2]     = o0;
  out[(size_t)t * EDIM + eo2 + 1] = o1;
}

// ---------------------------------------------------------------------------
extern "C" void kernel_launch(void* const* d_in, const int* in_sizes, int n_in,
                              void* d_out, int out_size, void* d_ws, size_t ws_size,
                              hipStream_t stream) {
  const float* x    = (const float*)d_in[0];
  const float* wihf = (const float*)d_in[1];
  const float* whhf = (const float*)d_in[2];
  const float* bf   = (const float*)d_in[3];
  const float* wihb = (const float*)d_in[4];
  const float* whhb = (const float*)d_in[5];
  const float* bbv  = (const float*)d_in[6];
  const float* te   = (const float*)d_in[7];
  const float* wq   = (const float*)d_in[8];
  const float* bq   = (const float*)d_in[9];
  const float* wk   = (const float*)d_in[10];
  const float* bk   = (const float*)d_in[11];
  const float* wvv  = (const float*)d_in[12];
  const float* bv   = (const float*)d_in[13];
  const float* wo   = (const float*)d_in[14];
  const float* bo   = (const float*)d_in[15];
  float* out = (float*)d_out;

  char* ws = (char*)d_ws;
  half_t* emb  = (half_t*)(ws + EMB_OFF);
  half_t* q_ws = (half_t*)(ws + Q_OFF);
  half_t* x16  = (half_t*)(ws + Q_OFF);     // aliased during LSTM phase
  half_t* wq16 = (half_t*)(ws + WQ_OFF);
  half_t* wk16 = (half_t*)(ws + WK_OFF);
  half_t* wv16 = (half_t*)(ws + WV_OFF);
  half_t* wo16 = (half_t*)(ws + WO_OFF);
  half_t* te16 = (half_t*)(ws + TE_OFF);

  convert_kernel<<<1808, 256, 0, stream>>>(wq, wk, wvv, wo, te, x,
                                           wq16, wk16, wv16, wo16, te16, x16);

  (void)hipFuncSetAttribute((const void*)lstm_kernel,
                            hipFuncAttributeMaxDynamicSharedMemorySize, LSTM_LDS_BYTES);
  lstm_kernel<<<64, 512, LSTM_LDS_BYTES, stream>>>(x16, wihf, whhf, bf, wihb, whhb, bbv, emb);

  qproj_kernel<<<64, 256, 0, stream>>>(emb, wq16, bq, q_ws);

  attn_kernel<<<2048, 256, 0, stream>>>(emb, q_ws, wk16, wv16, wo16, te16, bk, bv, bo, out);
}